// Round 1
// baseline (1055.198 us; speedup 1.0000x reference)
//
#include <hip/hip_runtime.h>
#include <cstdint>
#include <cstddef>

#define BB 4
#define NN 8192
#define MM 2048
#define KK 16
#define DP 128
#define DM 256
#define QROW 131  // 3 + 128 floats per query row
#define NQ 4      // queries per knn block
#define CAP2 384  // per-query candidate capacity

typedef __attribute__((ext_vector_type(8))) short short8;
typedef __attribute__((ext_vector_type(4))) float floatx4;

__device__ __forceinline__ unsigned short f2bf(float x) {
  unsigned u = __float_as_uint(x);
  unsigned r = (u + 0x7FFFu + ((u >> 16) & 1u)) >> 16;   // RNE
  return (unsigned short)r;
}

// Deterministic distance->sortable-key. Same DAG in every call site so both
// knn passes produce bit-identical keys. fmaf(-2,cr,t) == t - 2*cr exactly
// (2*cr is exact), matching the reference formula's final subtract.
__device__ __forceinline__ unsigned dkey(float qx, float qy, float qz, float q2,
                                         float xx, float xy, float xz, float x2) {
  float cr = fmaf(qz, xz, fmaf(qy, xy, qx * xx));
  float d  = fmaf(-2.0f, cr, q2 + x2);
  unsigned u = __float_as_uint(d);
  return (u & 0x80000000u) ? ~u : (u | 0x80000000u);  // ascending-sortable
}

// ---------------------------------------------------------------------------
// Kernel 0: weights f32->bf16, transposed to [N][K] (k-contig) back-to-back.
// ---------------------------------------------------------------------------
__global__ __launch_bounds__(256) void prep_weights(
    const float* __restrict__ wq, const float* __restrict__ fc1,
    const float* __restrict__ wk, const float* __restrict__ wv,
    const float* __restrict__ d2, const float* __restrict__ g1,
    const float* __restrict__ g2, const float* __restrict__ fc2,
    unsigned short* __restrict__ dst)
{
  long e = (long)blockIdx.x * 256 + threadIdx.x;
  if (e >= 425984) return;
  const float* src; int sh; int Nmat; long off;
  if (e < 32768)       { src = wq;  sh = 7; Nmat = 256; off = 0; }
  else if (e < 65536)  { src = fc1; sh = 7; Nmat = 256; off = 32768; }
  else if (e < 131072) { src = wk;  sh = 8; Nmat = 256; off = 65536; }
  else if (e < 196608) { src = wv;  sh = 8; Nmat = 256; off = 131072; }
  else if (e < 262144) { src = d2;  sh = 8; Nmat = 256; off = 196608; }
  else if (e < 327680) { src = g1;  sh = 8; Nmat = 256; off = 262144; }
  else if (e < 393216) { src = g2;  sh = 8; Nmat = 256; off = 327680; }
  else                 { src = fc2; sh = 8; Nmat = 128; off = 393216; }
  long d = e - off;
  int K = 1 << sh;
  int n = (int)(d >> sh), k = (int)(d & (K - 1));
  dst[e] = f2bf(src[(long)k * Nmat + n]);
}

// ---------------------------------------------------------------------------
// Kernel 1: exact KNN (k=16), 4 queries/block, no keys[] storage.
// Pass A: capped 256-bin histogram of key>>24 per query (point loads + x2
// shared across the 4 queries). Per-wave scan finds boundary bin B[q].
// Pass B: recompute keys (identical DAG), compact bins<=B into cand[q].
// Wave w does in-register argmin selection for query w. Rare >CAP fallback:
// 16 ascending rounds with (key,idx)-composite exclusion (exact top_k ties).
// ---------------------------------------------------------------------------
__global__ __launch_bounds__(256) void knn_kernel(
    const float* __restrict__ xyz, const float* __restrict__ query,
    int* __restrict__ knn_out)
{
  __shared__ int hist[NQ * 256];                    // 4 KB
  __shared__ unsigned long long cand[NQ][CAP2];     // 12 KB
  __shared__ int s_cnt[NQ];
  __shared__ int s_B[NQ];

  const int tid = threadIdx.x;
  const int l = tid & 63, w = tid >> 6;
  const int bm0 = blockIdx.x * NQ;
  const int b = bm0 >> 11;
  const float* X = xyz + (size_t)b * NN * 3;

  float qx[NQ], qy[NQ], qz[NQ], q2[NQ];
  #pragma unroll
  for (int q = 0; q < NQ; ++q) {
    const float* qp = query + (size_t)(bm0 + q) * QROW;
    qx[q] = qp[0]; qy[q] = qp[1]; qz[q] = qp[2];
    q2[q] = fmaf(qz[q], qz[q], fmaf(qy[q], qy[q], qx[q] * qx[q]));
  }

  #pragma unroll
  for (int i = 0; i < NQ; ++i) hist[tid + 256 * i] = 0;
  if (tid < NQ) s_cnt[tid] = 0;
  __syncthreads();

  // ---- Pass A: capped histograms ----
  for (int n = tid; n < NN; n += 256) {
    float xx = X[3*n], xy = X[3*n + 1], xz = X[3*n + 2];
    float x2 = fmaf(xz, xz, fmaf(xy, xy, xx * xx));
    #pragma unroll
    for (int q = 0; q < NQ; ++q) {
      unsigned u = dkey(qx[q], qy[q], qz[q], q2[q], xx, xy, xz, x2);
      int idx = q * 256 + (int)(u >> 24);
      if (((volatile int*)hist)[idx] < KK) atomicAdd(&hist[idx], 1);
    }
  }
  __syncthreads();

  // ---- Boundary scan: wave w handles query w; lane l covers bins 4l..4l+3.
  // Capped-cumsum boundary == true boundary (cap engages only at >=16). ----
  {
    int h0 = hist[w*256 + 4*l],     h1 = hist[w*256 + 4*l + 1];
    int h2 = hist[w*256 + 4*l + 2], h3 = hist[w*256 + 4*l + 3];
    int s = h0 + h1 + h2 + h3;
    int v = s;
    #pragma unroll
    for (int d = 1; d < 64; d <<= 1) {
      int o = __shfl_up(v, d, 64);
      if (l >= d) v += o;
    }
    int run = v - s;                       // exclusive prefix of bin 4l
    int in0 = run + h0;
    if (in0 >= KK && run < KK) s_B[w] = 4*l;
    run = in0; int in1 = run + h1;
    if (in1 >= KK && run < KK) s_B[w] = 4*l + 1;
    run = in1; int in2 = run + h2;
    if (in2 >= KK && run < KK) s_B[w] = 4*l + 2;
    run = in2; int in3 = run + h3;
    if (in3 >= KK && run < KK) s_B[w] = 4*l + 3;
  }
  __syncthreads();

  unsigned Bq[NQ];
  #pragma unroll
  for (int q = 0; q < NQ; ++q) Bq[q] = (unsigned)s_B[q];

  // ---- Pass B: recompute + compact candidates ----
  for (int n = tid; n < NN; n += 256) {
    float xx = X[3*n], xy = X[3*n + 1], xz = X[3*n + 2];
    float x2 = fmaf(xz, xz, fmaf(xy, xy, xx * xx));
    #pragma unroll
    for (int q = 0; q < NQ; ++q) {
      unsigned u = dkey(qx[q], qy[q], qz[q], q2[q], xx, xy, xz, x2);
      if ((u >> 24) <= Bq[q]) {
        int p = atomicAdd(&s_cnt[q], 1);
        if (p < CAP2) cand[q][p] = ((unsigned long long)u << 32) | (unsigned)n;
      }
    }
  }
  __syncthreads();

  const int cnt = s_cnt[w];
  const int bmw = bm0 + w;
  if (cnt <= CAP2) {
    // ---- Fast path: per-wave in-register selection, no barriers ----
    unsigned long long v[CAP2 / 64];
    #pragma unroll
    for (int i = 0; i < CAP2/64; ++i) {
      int p = i*64 + l;
      v[i] = (p < cnt) ? cand[w][p] : ~0ull;
    }
    for (int r = 0; r < KK; ++r) {
      unsigned long long m = v[0];
      #pragma unroll
      for (int i = 1; i < CAP2/64; ++i) m = v[i] < m ? v[i] : m;
      #pragma unroll
      for (int d = 32; d >= 1; d >>= 1) {
        unsigned long long o = __shfl_xor(m, d, 64);
        m = o < m ? o : m;
      }
      if (l == 0) knn_out[bmw*KK + r] = (int)(unsigned)(m & 0xffffffffu);
      #pragma unroll
      for (int i = 0; i < CAP2/64; ++i) if (v[i] == m) v[i] = ~0ull;
    }
  } else {
    // ---- Fallback (rare): 16 ascending rounds with composite exclusion ----
    const float* qp = query + (size_t)bmw * QROW;
    float fqx = qp[0], fqy = qp[1], fqz = qp[2];
    float fq2 = fmaf(fqz, fqz, fmaf(fqy, fqy, fqx * fqx));
    unsigned long long last = 0;
    for (int r = 0; r < KK; ++r) {
      unsigned long long best = ~0ull;
      for (int n = l; n < NN; n += 64) {
        float xx = X[3*n], xy = X[3*n + 1], xz = X[3*n + 2];
        float x2 = fmaf(xz, xz, fmaf(xy, xy, xx * xx));
        unsigned u = dkey(fqx, fqy, fqz, fq2, xx, xy, xz, x2);
        unsigned long long comp = ((unsigned long long)u << 32) | (unsigned)n;
        if (comp > last && comp < best) best = comp;
      }
      #pragma unroll
      for (int d = 32; d >= 1; d >>= 1) {
        unsigned long long o = __shfl_xor(best, d, 64);
        best = o < best ? o : best;
      }
      last = best;
      if (l == 0) knn_out[bmw*KK + r] = (int)(unsigned)(best & 0xffffffffu);
    }
  }
}

// ---------------------------------------------------------------------------
// Balanced MFMA tile-GEMM helper (unchanged): wave computes RT x 4 grid of
// 16x16 tiles; A from LDS, B 16B direct from global bf16 W^T[N][K].
// ---------------------------------------------------------------------------
template<int KT, int RT>
__device__ __forceinline__ void gemm_tiles(
    const unsigned short* aBase, int aStride,
    const unsigned short* __restrict__ bT,
    int lm, int lq, int colBase, int rtBase, floatx4 (&acc)[RT][4])
{
  #pragma unroll
  for (int ks = 0; ks < KT; ++ks) {
    short8 af[RT];
    #pragma unroll
    for (int rt = 0; rt < RT; ++rt)
      af[rt] = *(const short8*)&aBase[((rtBase + rt)*16 + lm)*aStride + ks*32 + lq*8];
    short8 bf[4];
    #pragma unroll
    for (int c = 0; c < 4; ++c)
      bf[c] = *(const short8*)&bT[(size_t)(colBase + c*16 + lm)*(KT*32) + ks*32 + lq*8];
    #pragma unroll
    for (int rt = 0; rt < RT; ++rt)
      #pragma unroll
      for (int c = 0; c < 4; ++c)
        acc[rt][c] = __builtin_amdgcn_mfma_f32_16x16x32_bf16(af[rt], bf[c], acc[rt][c], 0, 0, 0);
  }
}

// ---------------------------------------------------------------------------
// Kernel 2: fused block, 2 queries (32 rows) per 256-thread WG.
// LDS 40832 B -> 4 blocks/CU (16 waves) vs previous 2 (8 waves).
// Wave w owns cols [64w,64w+64). C-layout: col=lane&15, row=(lane>>4)*4+reg.
// ---------------------------------------------------------------------------
__global__ __launch_bounds__(256, 4) void fused_mfma(
    const float* __restrict__ xyz, const float* __restrict__ features,
    const float* __restrict__ query,
    const float* __restrict__ fc1_b, const float* __restrict__ fc2_b,
    const float* __restrict__ d1_w,  const float* __restrict__ d1_b,
    const float* __restrict__ d2_b,
    const float* __restrict__ g1_b,  const float* __restrict__ g2_b,
    const unsigned short* __restrict__ wT,
    const int* __restrict__ knn_idx,
    float* __restrict__ out_res, float* __restrict__ out_attn)
{
  const unsigned short* wq_t  = wT;
  const unsigned short* fc1_t = wT + 32768;
  const unsigned short* wk_t  = wT + 65536;
  const unsigned short* wv_t  = wT + 131072;
  const unsigned short* d2_t  = wT + 196608;
  const unsigned short* g1_t  = wT + 262144;
  const unsigned short* g2_t  = wT + 327680;
  const unsigned short* fc2_t = wT + 393216;

  __shared__ alignas(16) unsigned short bufA[32*264];  // feat(136) / h1 / a / rm
  __shared__ alignas(16) unsigned short bufB[32*264];  // x / h
  __shared__ alignas(16) unsigned short s_qf[16*136];  // query_f bf16 (rows 0..1)
  __shared__ alignas(16) float s_q[2*256];             // q projection (f32)
  __shared__ float s_delta[32][4];
  __shared__ int   s_idx[32];

  const int tid = threadIdx.x;
  const int l  = tid & 63, w = tid >> 6;
  const int lm = l & 15,  lq = l >> 4;
  const int colBase = w * 64;
  const int bm0 = blockIdx.x << 1;
  const int b   = bm0 >> 11;

  // ---- Phase 0: indices, delta, query_f, feature gather ----
  if (tid < 32) {
    int q = tid >> 4, n = tid & 15;
    int idx = knn_idx[(bm0 + q)*KK + n];
    s_idx[tid] = idx;
    const float* qp = query + (size_t)(bm0 + q) * QROW;
    const float* xp = xyz + ((size_t)b*NN + idx)*3;
    s_delta[tid][0] = qp[0] - xp[0];
    s_delta[tid][1] = qp[1] - xp[1];
    s_delta[tid][2] = qp[2] - xp[2];
  }
  if (tid < 128) {
    int e = tid * 2;                    // 256 elems: rows 0..1 x 128 cols
    int q = e >> 7, c = e & 127;
    const float* qp = query + (size_t)(bm0 + q)*QROW + 3 + c;
    unsigned v = ((unsigned)f2bf(qp[1]) << 16) | f2bf(qp[0]);
    *(unsigned*)&s_qf[q*136 + c] = v;
  }
  __syncthreads();
  {
    int r = tid >> 3, c0 = (tid & 7) * 16;
    const float4* fp4 = (const float4*)(features + ((size_t)b*NN + s_idx[r])*DP + c0);
    unsigned short* dst = &bufA[r*136 + c0];
    #pragma unroll
    for (int i = 0; i < 4; ++i) {
      float4 v4 = fp4[i];
      *(unsigned*)&dst[i*4]     = ((unsigned)f2bf(v4.y) << 16) | f2bf(v4.x);
      *(unsigned*)&dst[i*4 + 2] = ((unsigned)f2bf(v4.w) << 16) | f2bf(v4.z);
    }
  }
  __syncthreads();

  const floatx4 zero4 = {0.f, 0.f, 0.f, 0.f};

  // ---- Phase 1: x = feat @ fc1 + b  -> bufB ;  q = qf @ wq -> s_q ----
  {
    floatx4 acc[2][4];
    #pragma unroll
    for (int rt = 0; rt < 2; ++rt)
      #pragma unroll
      for (int c = 0; c < 4; ++c) acc[rt][c] = zero4;
    gemm_tiles<4,2>(bufA, 136, fc1_t, lm, lq, colBase, 0, acc);
    #pragma unroll
    for (int c = 0; c < 4; ++c) {
      float bias = fc1_b[colBase + c*16 + lm];
      #pragma unroll
      for (int rt = 0; rt < 2; ++rt)
        #pragma unroll
        for (int r = 0; r < 4; ++r)
          bufB[(rt*16 + lq*4 + r)*264 + colBase + c*16 + lm] = f2bf(acc[rt][c][r] + bias);
    }
  }
  {
    floatx4 qa[1][4];
    #pragma unroll
    for (int c = 0; c < 4; ++c) qa[0][c] = zero4;
    gemm_tiles<4,1>(s_qf, 136, wq_t, lm, lq, colBase, 0, qa);
    if (lq == 0) {
      #pragma unroll
      for (int c = 0; c < 4; ++c)
        #pragma unroll
        for (int r = 0; r < 2; ++r)
          s_q[r*256 + colBase + c*16 + lm] = qa[0][c][r];   // row r == query r
    }
  }
  __syncthreads();   // x visible; bufA(feat) dead

  // ---- Phase 2: h1 = relu(delta @ d1 + b) -> bufA (VALU, tiny K=3) ----
  {
    int c = tid;
    float w0 = d1_w[c], w1 = d1_w[256 + c], w2 = d1_w[512 + c], bb = d1_b[c];
    #pragma unroll 4
    for (int r = 0; r < 32; ++r) {
      float v = fmaf(s_delta[r][2], w2, fmaf(s_delta[r][1], w1,
                fmaf(s_delta[r][0], w0, bb)));
      bufA[r*264 + c] = f2bf(v > 0.f ? v : 0.f);
    }
  }
  __syncthreads();   // h1 visible

  // ---- Phase 3: pe = h1 @ d2 + b (regs, persistent) ----
  floatx4 pe[2][4];
  #pragma unroll
  for (int rt = 0; rt < 2; ++rt)
    #pragma unroll
    for (int c = 0; c < 4; ++c) pe[rt][c] = zero4;
  gemm_tiles<8,2>(bufA, 264, d2_t, lm, lq, colBase, 0, pe);
  #pragma unroll
  for (int c = 0; c < 4; ++c) {
    float bias = d2_b[colBase + c*16 + lm];
    #pragma unroll
    for (int rt = 0; rt < 2; ++rt)
      #pragma unroll
      for (int r = 0; r < 4; ++r) pe[rt][c][r] += bias;
  }

  // ---- Phase 4: vpe = x @ wv + pe (regs, persistent) ----
  floatx4 vpe[2][4];
  #pragma unroll
  for (int rt = 0; rt < 2; ++rt)
    #pragma unroll
    for (int c = 0; c < 4; ++c) vpe[rt][c] = zero4;
  gemm_tiles<8,2>(bufB, 264, wv_t, lm, lq, colBase, 0, vpe);
  #pragma unroll
  for (int rt = 0; rt < 2; ++rt)
    #pragma unroll
    for (int c = 0; c < 4; ++c)
      #pragma unroll
      for (int r = 0; r < 4; ++r)
        vpe[rt][c][r] += pe[rt][c][r];
  __syncthreads();   // all waves done reading bufA(h1); a-writes may begin

  // ---- Phase 5: k = x @ wk ; a = q - k + pe -> bufA ----
  {
    floatx4 kacc[2][4];
    #pragma unroll
    for (int rt = 0; rt < 2; ++rt)
      #pragma unroll
      for (int c = 0; c < 4; ++c) kacc[rt][c] = zero4;
    gemm_tiles<8,2>(bufB, 264, wk_t, lm, lq, colBase, 0, kacc);
    #pragma unroll
    for (int rt = 0; rt < 2; ++rt) {
      #pragma unroll
      for (int c = 0; c < 4; ++c) {
        float qv = s_q[rt*256 + colBase + c*16 + lm];
        #pragma unroll
        for (int r = 0; r < 4; ++r) {
          float a = qv - kacc[rt][c][r] + pe[rt][c][r];
          bufA[(rt*16 + lq*4 + r)*264 + colBase + c*16 + lm] = f2bf(a);
        }
      }
    }
  }
  __syncthreads();   // a visible; bufB(x) dead

  // ---- Phase 6: h = relu(a @ g1 + b) -> bufB ----
  {
    floatx4 h[2][4];
    #pragma unroll
    for (int rt = 0; rt < 2; ++rt)
      #pragma unroll
      for (int c = 0; c < 4; ++c) h[rt][c] = zero4;
    gemm_tiles<8,2>(bufA, 264, g1_t, lm, lq, colBase, 0, h);
    #pragma unroll
    for (int c = 0; c < 4; ++c) {
      float bias = g1_b[colBase + c*16 + lm];
      #pragma unroll
      for (int rt = 0; rt < 2; ++rt)
        #pragma unroll
        for (int r = 0; r < 4; ++r) {
          float v = h[rt][c][r] + bias;
          bufB[(rt*16 + lq*4 + r)*264 + colBase + c*16 + lm] = f2bf(v > 0.f ? v : 0.f);
        }
    }
  }
  __syncthreads();   // h visible; bufA(a) dead -> reuse as s_rm

  // ---- Phase 7/8: per-query logits = h @ g2 + b, softmax over neighbors,
  //      attn store, rm = sum_n attn * vpe ----
  unsigned short* s_rm = bufA;   // [16][264], rows 0..1 valid
  #pragma unroll
  for (int rt = 0; rt < 2; ++rt) {
    floatx4 lg[1][4];
    #pragma unroll
    for (int c = 0; c < 4; ++c) lg[0][c] = zero4;
    gemm_tiles<8,1>(bufB, 264, g2_t, lm, lq, colBase, rt, lg);
    #pragma unroll
    for (int c = 0; c < 4; ++c) {
      float bias = g2_b[colBase + c*16 + lm];
      float v[4];
      float mx = -INFINITY;
      #pragma unroll
      for (int r = 0; r < 4; ++r) {
        v[r] = (lg[0][c][r] + bias) * 0.0625f;
        mx = fmaxf(mx, v[r]);
      }
      mx = fmaxf(mx, __shfl_xor(mx, 16, 64));
      mx = fmaxf(mx, __shfl_xor(mx, 32, 64));
      float s = 0.f;
      #pragma unroll
      for (int r = 0; r < 4; ++r) { v[r] = __expf(v[r] - mx); s += v[r]; }
      s += __shfl_xor(s, 16, 64);
      s += __shfl_xor(s, 32, 64);
      float inv = 1.0f / s;
      float rm = 0.f;
      size_t abase = ((size_t)(bm0 + rt)*KK)*DM + colBase + c*16 + lm;
      #pragma unroll
      for (int r = 0; r < 4; ++r) {
        float at = v[r] * inv;
        out_attn[abase + (size_t)(lq*4 + r)*DM] = at;
        rm = fmaf(at, vpe[rt][c][r], rm);
      }
      rm += __shfl_xor(rm, 16, 64);
      rm += __shfl_xor(rm, 32, 64);
      if (lq == 0) s_rm[rt*264 + colBase + c*16 + lm] = f2bf(rm);
    }
  }
  __syncthreads();

  // ---- Phase 9: res = rm @ fc2 + b + query_f ----
  {
    floatx4 acc[2];
    acc[0] = zero4; acc[1] = zero4;
    #pragma unroll
    for (int ks = 0; ks < 8; ++ks) {
      short8 af = *(const short8*)&s_rm[lm*264 + ks*32 + lq*8];
      #pragma unroll
      for (int c = 0; c < 2; ++c) {
        int col = (w*2 + c)*16 + lm;
        short8 bf = *(const short8*)&fc2_t[(size_t)col*256 + ks*32 + lq*8];
        acc[c] = __builtin_amdgcn_mfma_f32_16x16x32_bf16(af, bf, acc[c], 0, 0, 0);
      }
    }
    if (lq == 0) {
      #pragma unroll
      for (int c = 0; c < 2; ++c) {
        int col = (w*2 + c)*16 + lm;
        float bias = fc2_b[col];
        #pragma unroll
        for (int r = 0; r < 2; ++r) {
          float res = acc[c][r] + bias + query[(size_t)(bm0 + r)*QROW + 3 + col];
          out_res[(size_t)(bm0 + r)*DP + col] = res;
        }
      }
    }
  }
}

extern "C" void kernel_launch(void* const* d_in, const int* in_sizes, int n_in,
                              void* d_out, int out_size, void* d_ws, size_t ws_size,
                              hipStream_t stream) {
  const float* xyz      = (const float*)d_in[0];
  const float* features = (const float*)d_in[1];
  const float* query    = (const float*)d_in[2];
  const float* fc1_w    = (const float*)d_in[3];
  const float* fc1_b    = (const float*)d_in[4];
  const float* fc2_w    = (const float*)d_in[5];
  const float* fc2_b    = (const float*)d_in[6];
  const float* d1_w     = (const float*)d_in[7];
  const float* d1_b     = (const float*)d_in[8];
  const float* d2_w     = (const float*)d_in[9];
  const float* d2_b     = (const float*)d_in[10];
  const float* g1_w     = (const float*)d_in[11];
  const float* g1_b     = (const float*)d_in[12];
  const float* g2_w     = (const float*)d_in[13];
  const float* g2_b     = (const float*)d_in[14];
  const float* wq       = (const float*)d_in[15];
  const float* wk       = (const float*)d_in[16];
  const float* wv       = (const float*)d_in[17];

  int* knn = (int*)d_ws;                                          // 512 KB
  unsigned short* wT = (unsigned short*)((char*)d_ws + 524288);   // 832 KB bf16
  float* out_res  = (float*)d_out;
  float* out_attn = (float*)d_out + (size_t)BB*MM*DP;

  prep_weights<<<1664, 256, 0, stream>>>(wq, fc1_w, wk, wv, d2_w, g1_w, g2_w, fc2_w, wT);
  knn_kernel<<<BB*MM/NQ, 256, 0, stream>>>(xyz, query, knn);
  fused_mfma<<<BB*MM/2, 256, 0, stream>>>(
      xyz, features, query, fc1_b, fc2_b, d1_w, d1_b, d2_b, g1_b, g2_b,
      wT, knn, out_res, out_attn);
}

// Round 2
// 722.140 us; speedup vs baseline: 1.4612x; 1.4612x over previous
//
#include <hip/hip_runtime.h>
#include <cstdint>
#include <cstddef>

#define BB 4
#define NN 8192
#define MM 2048
#define KK 16
#define DP 128
#define DM 256
#define QROW 131  // 3 + 128 floats per query row
#define NQ 4      // queries per knn block (one per wave)
#define CAP2 384  // per-query candidate capacity

typedef __attribute__((ext_vector_type(8))) short short8;
typedef __attribute__((ext_vector_type(4))) float floatx4;

__device__ __forceinline__ unsigned short f2bf(float x) {
  unsigned u = __float_as_uint(x);
  unsigned r = (u + 0x7FFFu + ((u >> 16) & 1u)) >> 16;   // RNE
  return (unsigned short)r;
}

// Deterministic distance->sortable-key. Same DAG everywhere so threshold
// comparisons and final selection are in one consistent key space.
__device__ __forceinline__ unsigned dkey(float qx, float qy, float qz, float q2,
                                         float xx, float xy, float xz, float x2) {
  float cr = fmaf(qz, xz, fmaf(qy, xy, qx * xx));
  float d  = fmaf(-2.0f, cr, q2 + x2);
  unsigned u = __float_as_uint(d);
  return (u & 0x80000000u) ? ~u : (u | 0x80000000u);  // ascending-sortable
}

// ---------------------------------------------------------------------------
// Kernel 0: weights f32->bf16, transposed to [N][K] (k-contig) back-to-back.
// wk segment stored NEGATED so the fused kernel can compute
// a = (q + pe) + x@(-wk) as a single MFMA accumulation (kills the register
// peak that was spilling to scratch).
// ---------------------------------------------------------------------------
__global__ __launch_bounds__(256) void prep_weights(
    const float* __restrict__ wq, const float* __restrict__ fc1,
    const float* __restrict__ wk, const float* __restrict__ wv,
    const float* __restrict__ d2, const float* __restrict__ g1,
    const float* __restrict__ g2, const float* __restrict__ fc2,
    unsigned short* __restrict__ dst)
{
  long e = (long)blockIdx.x * 256 + threadIdx.x;
  if (e >= 425984) return;
  const float* src; int sh; int Nmat; long off; bool neg = false;
  if (e < 32768)       { src = wq;  sh = 7; Nmat = 256; off = 0; }
  else if (e < 65536)  { src = fc1; sh = 7; Nmat = 256; off = 32768; }
  else if (e < 131072) { src = wk;  sh = 8; Nmat = 256; off = 65536; neg = true; }
  else if (e < 196608) { src = wv;  sh = 8; Nmat = 256; off = 131072; }
  else if (e < 262144) { src = d2;  sh = 8; Nmat = 256; off = 196608; }
  else if (e < 327680) { src = g1;  sh = 8; Nmat = 256; off = 262144; }
  else if (e < 393216) { src = g2;  sh = 8; Nmat = 256; off = 327680; }
  else                 { src = fc2; sh = 8; Nmat = 128; off = 393216; }
  long d = e - off;
  int K = 1 << sh;
  int n = (int)(d >> sh), k = (int)(d & (K - 1));
  float v = src[(long)k * Nmat + n];
  dst[e] = f2bf(neg ? -v : v);
}

// ---------------------------------------------------------------------------
// Kernel 1: exact KNN (k=16), one query PER WAVE, no barriers/histograms.
// Stage 1: 1024-point sample -> in-register extract 16 smallest keys; T =
//   16th extracted. Subset k-th >= population k-th, so T >= true d16 key
//   (duplicate bulk-removal only raises T; <16 distinct keys -> T=UINT_MAX
//   -> fallback). So {u <= T} is a superset of the true top-16.
// Stage 2: filtered scan of all 8192 pushes candidates (E[cnt]~130, >=16
//   guaranteed since the sample's own 16 pass).
// Stage 3: composite (key,idx) in-register selection (exact top_k ties).
// ---------------------------------------------------------------------------
__global__ __launch_bounds__(256) void knn_kernel(
    const float* __restrict__ xyz, const float* __restrict__ query,
    int* __restrict__ knn_out)
{
  __shared__ unsigned long long cand[NQ][CAP2];     // 12 KB
  __shared__ int s_cnt[NQ];

  const int tid = threadIdx.x;
  const int l = tid & 63, w = tid >> 6;
  const int bmw = blockIdx.x * NQ + w;
  const int b = bmw >> 11;
  const float* X = xyz + (size_t)b * NN * 3;
  const float* qp = query + (size_t)bmw * QROW;
  const float qx = qp[0], qy = qp[1], qz = qp[2];
  const float q2 = fmaf(qz, qz, fmaf(qy, qy, qx * qx));

  if (tid < NQ) s_cnt[tid] = 0;
  __syncthreads();

  // ---- Stage 1: sample 1024 points, extract threshold ----
  unsigned sk[16];
  #pragma unroll
  for (int i = 0; i < 16; ++i) {
    int n = i * 64 + l;
    float xx = X[3*n], xy = X[3*n + 1], xz = X[3*n + 2];
    float x2 = fmaf(xz, xz, fmaf(xy, xy, xx * xx));
    sk[i] = dkey(qx, qy, qz, q2, xx, xy, xz, x2);
  }
  unsigned T = 0xFFFFFFFFu;
  for (int r = 0; r < KK; ++r) {
    unsigned m = sk[0];
    #pragma unroll
    for (int i = 1; i < 16; ++i) m = sk[i] < m ? sk[i] : m;
    #pragma unroll
    for (int d = 32; d >= 1; d >>= 1) {
      unsigned o = __shfl_xor(m, d, 64);
      m = o < m ? o : m;
    }
    T = m;
    #pragma unroll
    for (int i = 0; i < 16; ++i) if (sk[i] == m) sk[i] = 0xFFFFFFFFu;
  }

  // ---- Stage 2: filtered full scan ----
  for (int n = l; n < NN; n += 64) {
    float xx = X[3*n], xy = X[3*n + 1], xz = X[3*n + 2];
    float x2 = fmaf(xz, xz, fmaf(xy, xy, xx * xx));
    unsigned u = dkey(qx, qy, qz, q2, xx, xy, xz, x2);
    if (u <= T) {
      int p = atomicAdd(&s_cnt[w], 1);
      if (p < CAP2) cand[w][p] = ((unsigned long long)u << 32) | (unsigned)n;
    }
  }
  const int cnt = s_cnt[w];   // wave-internal DS ops are ordered; no barrier

  if (cnt <= CAP2) {
    // ---- Stage 3: in-register selection ----
    unsigned long long v[CAP2 / 64];
    #pragma unroll
    for (int i = 0; i < CAP2/64; ++i) {
      int p = i*64 + l;
      v[i] = (p < cnt) ? cand[w][p] : ~0ull;
    }
    for (int r = 0; r < KK; ++r) {
      unsigned long long m = v[0];
      #pragma unroll
      for (int i = 1; i < CAP2/64; ++i) m = v[i] < m ? v[i] : m;
      #pragma unroll
      for (int d = 32; d >= 1; d >>= 1) {
        unsigned long long o = __shfl_xor(m, d, 64);
        m = o < m ? o : m;
      }
      if (l == 0) knn_out[bmw*KK + r] = (int)(unsigned)(m & 0xffffffffu);
      #pragma unroll
      for (int i = 0; i < CAP2/64; ++i) if (v[i] == m) v[i] = ~0ull;
    }
  } else {
    // ---- Fallback (prob ~0): 16 ascending rounds with composite exclusion ----
    unsigned long long last = 0;
    for (int r = 0; r < KK; ++r) {
      unsigned long long best = ~0ull;
      for (int n = l; n < NN; n += 64) {
        float xx = X[3*n], xy = X[3*n + 1], xz = X[3*n + 2];
        float x2 = fmaf(xz, xz, fmaf(xy, xy, xx * xx));
        unsigned u = dkey(qx, qy, qz, q2, xx, xy, xz, x2);
        unsigned long long comp = ((unsigned long long)u << 32) | (unsigned)n;
        if (comp > last && comp < best) best = comp;
      }
      #pragma unroll
      for (int d = 32; d >= 1; d >>= 1) {
        unsigned long long o = __shfl_xor(best, d, 64);
        best = o < best ? o : best;
      }
      last = best;
      if (l == 0) knn_out[bmw*KK + r] = (int)(unsigned)(best & 0xffffffffu);
    }
  }
}

// ---------------------------------------------------------------------------
// Balanced MFMA tile-GEMM helper: wave computes RT x 4 grid of 16x16 tiles;
// A from LDS, B 16B direct from global bf16 W^T[N][K]. Accumulates into acc
// (callers may pre-initialize acc to fold C-init for free).
// ---------------------------------------------------------------------------
template<int KT, int RT>
__device__ __forceinline__ void gemm_tiles(
    const unsigned short* aBase, int aStride,
    const unsigned short* __restrict__ bT,
    int lm, int lq, int colBase, int rtBase, floatx4 (&acc)[RT][4])
{
  #pragma unroll
  for (int ks = 0; ks < KT; ++ks) {
    short8 af[RT];
    #pragma unroll
    for (int rt = 0; rt < RT; ++rt)
      af[rt] = *(const short8*)&aBase[((rtBase + rt)*16 + lm)*aStride + ks*32 + lq*8];
    short8 bf[4];
    #pragma unroll
    for (int c = 0; c < 4; ++c)
      bf[c] = *(const short8*)&bT[(size_t)(colBase + c*16 + lm)*(KT*32) + ks*32 + lq*8];
    #pragma unroll
    for (int rt = 0; rt < RT; ++rt)
      #pragma unroll
      for (int c = 0; c < 4; ++c)
        acc[rt][c] = __builtin_amdgcn_mfma_f32_16x16x32_bf16(af[rt], bf[c], acc[rt][c], 0, 0, 0);
  }
}

// ---------------------------------------------------------------------------
// Kernel 2: fused block, 2 queries (32 rows) per 256-thread WG, 4 blocks/CU.
// Register discipline: concurrent MFMA accumulators capped at 64 f32/thread
// (pe+vpe, vpe+a, vpe+h, vpe+lg) so the 128-reg budget at 4 waves/EU holds
// with ZERO scratch (r1 spilled ~600 MB). pe dies into the a-init; wk is
// pre-negated so a = (q+pe) + x@(-wk) is one accumulation.
// ---------------------------------------------------------------------------
__global__ __launch_bounds__(256, 4) void fused_mfma(
    const float* __restrict__ xyz, const float* __restrict__ features,
    const float* __restrict__ query,
    const float* __restrict__ fc1_b, const float* __restrict__ fc2_b,
    const float* __restrict__ d1_w,  const float* __restrict__ d1_b,
    const float* __restrict__ d2_b,
    const float* __restrict__ g1_b,  const float* __restrict__ g2_b,
    const unsigned short* __restrict__ wT,
    const int* __restrict__ knn_idx,
    float* __restrict__ out_res, float* __restrict__ out_attn)
{
  const unsigned short* wq_t  = wT;
  const unsigned short* fc1_t = wT + 32768;
  const unsigned short* wkN_t = wT + 65536;    // negated
  const unsigned short* wv_t  = wT + 131072;
  const unsigned short* d2_t  = wT + 196608;
  const unsigned short* g1_t  = wT + 262144;
  const unsigned short* g2_t  = wT + 327680;
  const unsigned short* fc2_t = wT + 393216;

  __shared__ alignas(16) unsigned short bufA[32*264];  // feat(136) / h1 / a / rm
  __shared__ alignas(16) unsigned short bufB[32*264];  // x / h
  __shared__ alignas(16) unsigned short s_qf[16*136];  // query_f bf16 (rows 0..1)
  __shared__ alignas(16) float s_q[2*256];             // q projection (f32)
  __shared__ float s_delta[32][4];
  __shared__ int   s_idx[32];

  const int tid = threadIdx.x;
  const int l  = tid & 63, w = tid >> 6;
  const int lm = l & 15,  lq = l >> 4;
  const int colBase = w * 64;
  const int bm0 = blockIdx.x << 1;
  const int b   = bm0 >> 11;

  // ---- Phase 0: indices, delta, query_f, feature gather ----
  if (tid < 32) {
    int q = tid >> 4, n = tid & 15;
    int idx = knn_idx[(bm0 + q)*KK + n];
    s_idx[tid] = idx;
    const float* qp = query + (size_t)(bm0 + q) * QROW;
    const float* xp = xyz + ((size_t)b*NN + idx)*3;
    s_delta[tid][0] = qp[0] - xp[0];
    s_delta[tid][1] = qp[1] - xp[1];
    s_delta[tid][2] = qp[2] - xp[2];
  }
  if (tid < 128) {
    int e = tid * 2;                    // 256 elems: rows 0..1 x 128 cols
    int q = e >> 7, c = e & 127;
    const float* qp = query + (size_t)(bm0 + q)*QROW + 3 + c;
    unsigned v = ((unsigned)f2bf(qp[1]) << 16) | f2bf(qp[0]);
    *(unsigned*)&s_qf[q*136 + c] = v;
  }
  __syncthreads();
  {
    int r = tid >> 3, c0 = (tid & 7) * 16;
    const float4* fp4 = (const float4*)(features + ((size_t)b*NN + s_idx[r])*DP + c0);
    unsigned short* dst = &bufA[r*136 + c0];
    #pragma unroll
    for (int i = 0; i < 4; ++i) {
      float4 v4 = fp4[i];
      *(unsigned*)&dst[i*4]     = ((unsigned)f2bf(v4.y) << 16) | f2bf(v4.x);
      *(unsigned*)&dst[i*4 + 2] = ((unsigned)f2bf(v4.w) << 16) | f2bf(v4.z);
    }
  }
  __syncthreads();

  const floatx4 zero4 = {0.f, 0.f, 0.f, 0.f};

  // ---- Phase 1: x = feat @ fc1 + b  -> bufB ;  q = qf @ wq -> s_q ----
  {
    floatx4 acc[2][4];
    #pragma unroll
    for (int rt = 0; rt < 2; ++rt)
      #pragma unroll
      for (int c = 0; c < 4; ++c) acc[rt][c] = zero4;
    gemm_tiles<4,2>(bufA, 136, fc1_t, lm, lq, colBase, 0, acc);
    #pragma unroll
    for (int c = 0; c < 4; ++c) {
      float bias = fc1_b[colBase + c*16 + lm];
      #pragma unroll
      for (int rt = 0; rt < 2; ++rt)
        #pragma unroll
        for (int r = 0; r < 4; ++r)
          bufB[(rt*16 + lq*4 + r)*264 + colBase + c*16 + lm] = f2bf(acc[rt][c][r] + bias);
    }
  }
  {
    floatx4 qa[1][4];
    #pragma unroll
    for (int c = 0; c < 4; ++c) qa[0][c] = zero4;
    gemm_tiles<4,1>(s_qf, 136, wq_t, lm, lq, colBase, 0, qa);
    if (lq == 0) {
      #pragma unroll
      for (int c = 0; c < 4; ++c)
        #pragma unroll
        for (int r = 0; r < 2; ++r)
          s_q[r*256 + colBase + c*16 + lm] = qa[0][c][r];   // row r == query r
    }
  }
  __syncthreads();   // x visible; bufA(feat) dead

  // ---- Phase 2: h1 = relu(delta @ d1 + b) -> bufA (VALU, tiny K=3) ----
  {
    int c = tid;
    float w0 = d1_w[c], w1 = d1_w[256 + c], w2 = d1_w[512 + c], bb = d1_b[c];
    #pragma unroll 4
    for (int r = 0; r < 32; ++r) {
      float v = fmaf(s_delta[r][2], w2, fmaf(s_delta[r][1], w1,
                fmaf(s_delta[r][0], w0, bb)));
      bufA[r*264 + c] = f2bf(v > 0.f ? v : 0.f);
    }
  }
  __syncthreads();   // h1 visible

  // ---- Phase 3: pe = h1 @ d2 + b (regs; acc set #1) ----
  floatx4 pe[2][4];
  #pragma unroll
  for (int rt = 0; rt < 2; ++rt)
    #pragma unroll
    for (int c = 0; c < 4; ++c) pe[rt][c] = zero4;
  gemm_tiles<8,2>(bufA, 264, d2_t, lm, lq, colBase, 0, pe);
  #pragma unroll
  for (int c = 0; c < 4; ++c) {
    float bias = d2_b[colBase + c*16 + lm];
    #pragma unroll
    for (int rt = 0; rt < 2; ++rt)
      #pragma unroll
      for (int r = 0; r < 4; ++r) pe[rt][c][r] += bias;
  }

  // ---- Phase 4: vpe = x @ wv + pe (acc set #2 initialized from pe) ----
  floatx4 vpe[2][4];
  #pragma unroll
  for (int rt = 0; rt < 2; ++rt)
    #pragma unroll
    for (int c = 0; c < 4; ++c) vpe[rt][c] = pe[rt][c];
  gemm_tiles<8,2>(bufB, 264, wv_t, lm, lq, colBase, 0, vpe);
  __syncthreads();   // all waves done reading bufA(h1); a-writes may begin

  // ---- Phase 5: a = (q + pe) + x @ (-wk) -> bufA ; pe dies in the init ----
  {
    floatx4 acc[2][4];
    #pragma unroll
    for (int rt = 0; rt < 2; ++rt)
      #pragma unroll
      for (int c = 0; c < 4; ++c) {
        float qv = s_q[rt*256 + colBase + c*16 + lm];
        #pragma unroll
        for (int r = 0; r < 4; ++r) acc[rt][c][r] = qv + pe[rt][c][r];
      }
    gemm_tiles<8,2>(bufB, 264, wkN_t, lm, lq, colBase, 0, acc);
    #pragma unroll
    for (int rt = 0; rt < 2; ++rt)
      #pragma unroll
      for (int c = 0; c < 4; ++c)
        #pragma unroll
        for (int r = 0; r < 4; ++r)
          bufA[(rt*16 + lq*4 + r)*264 + colBase + c*16 + lm] = f2bf(acc[rt][c][r]);
  }
  __syncthreads();   // a visible; bufB(x) dead

  // ---- Phase 6: h = relu(a @ g1 + b) -> bufB ----
  {
    floatx4 h[2][4];
    #pragma unroll
    for (int rt = 0; rt < 2; ++rt)
      #pragma unroll
      for (int c = 0; c < 4; ++c) h[rt][c] = zero4;
    gemm_tiles<8,2>(bufA, 264, g1_t, lm, lq, colBase, 0, h);
    #pragma unroll
    for (int c = 0; c < 4; ++c) {
      float bias = g1_b[colBase + c*16 + lm];
      #pragma unroll
      for (int rt = 0; rt < 2; ++rt)
        #pragma unroll
        for (int r = 0; r < 4; ++r) {
          float v = h[rt][c][r] + bias;
          bufB[(rt*16 + lq*4 + r)*264 + colBase + c*16 + lm] = f2bf(v > 0.f ? v : 0.f);
        }
    }
  }
  __syncthreads();   // h visible; bufA(a) dead -> reuse as s_rm

  // ---- Phase 7/8: lg = h @ g2 + b (both rt at once), softmax over
  //      neighbors, nontemporal attn store, rm = sum_n attn * vpe ----
  unsigned short* s_rm = bufA;   // [16][264], rows 0..1 valid
  {
    floatx4 lg[2][4];
    #pragma unroll
    for (int rt = 0; rt < 2; ++rt)
      #pragma unroll
      for (int c = 0; c < 4; ++c) lg[rt][c] = zero4;
    gemm_tiles<8,2>(bufB, 264, g2_t, lm, lq, colBase, 0, lg);
    #pragma unroll
    for (int rt = 0; rt < 2; ++rt) {
      #pragma unroll
      for (int c = 0; c < 4; ++c) {
        float bias = g2_b[colBase + c*16 + lm];
        float v[4];
        float mx = -INFINITY;
        #pragma unroll
        for (int r = 0; r < 4; ++r) {
          v[r] = (lg[rt][c][r] + bias) * 0.0625f;
          mx = fmaxf(mx, v[r]);
        }
        mx = fmaxf(mx, __shfl_xor(mx, 16, 64));
        mx = fmaxf(mx, __shfl_xor(mx, 32, 64));
        float s = 0.f;
        #pragma unroll
        for (int r = 0; r < 4; ++r) { v[r] = __expf(v[r] - mx); s += v[r]; }
        s += __shfl_xor(s, 16, 64);
        s += __shfl_xor(s, 32, 64);
        float inv = 1.0f / s;
        float rm = 0.f;
        size_t abase = ((size_t)(bm0 + rt)*KK)*DM + colBase + c*16 + lm;
        #pragma unroll
        for (int r = 0; r < 4; ++r) {
          float at = v[r] * inv;
          __builtin_nontemporal_store(at, &out_attn[abase + (size_t)(lq*4 + r)*DM]);
          rm = fmaf(at, vpe[rt][c][r], rm);
        }
        rm += __shfl_xor(rm, 16, 64);
        rm += __shfl_xor(rm, 32, 64);
        if (lq == 0) s_rm[rt*264 + colBase + c*16 + lm] = f2bf(rm);
      }
    }
  }
  __syncthreads();

  // ---- Phase 9: res = rm @ fc2 + b + query_f ----
  {
    floatx4 acc[2];
    acc[0] = zero4; acc[1] = zero4;
    #pragma unroll
    for (int ks = 0; ks < 8; ++ks) {
      short8 af = *(const short8*)&s_rm[lm*264 + ks*32 + lq*8];
      #pragma unroll
      for (int c = 0; c < 2; ++c) {
        int col = (w*2 + c)*16 + lm;
        short8 bf = *(const short8*)&fc2_t[(size_t)col*256 + ks*32 + lq*8];
        acc[c] = __builtin_amdgcn_mfma_f32_16x16x32_bf16(af, bf, acc[c], 0, 0, 0);
      }
    }
    if (lq == 0) {
      #pragma unroll
      for (int c = 0; c < 2; ++c) {
        int col = (w*2 + c)*16 + lm;
        float bias = fc2_b[col];
        #pragma unroll
        for (int r = 0; r < 2; ++r) {
          float res = acc[c][r] + bias + query[(size_t)(bm0 + r)*QROW + 3 + col];
          __builtin_nontemporal_store(res, &out_res[(size_t)(bm0 + r)*DP + col]);
        }
      }
    }
  }
}

extern "C" void kernel_launch(void* const* d_in, const int* in_sizes, int n_in,
                              void* d_out, int out_size, void* d_ws, size_t ws_size,
                              hipStream_t stream) {
  const float* xyz      = (const float*)d_in[0];
  const float* features = (const float*)d_in[1];
  const float* query    = (const float*)d_in[2];
  const float* fc1_w    = (const float*)d_in[3];
  const float* fc1_b    = (const float*)d_in[4];
  const float* fc2_w    = (const float*)d_in[5];
  const float* fc2_b    = (const float*)d_in[6];
  const float* d1_w     = (const float*)d_in[7];
  const float* d1_b     = (const float*)d_in[8];
  const float* d2_w     = (const float*)d_in[9];
  const float* d2_b     = (const float*)d_in[10];
  const float* g1_w     = (const float*)d_in[11];
  const float* g1_b     = (const float*)d_in[12];
  const float* g2_w     = (const float*)d_in[13];
  const float* g2_b     = (const float*)d_in[14];
  const float* wq       = (const float*)d_in[15];
  const float* wk       = (const float*)d_in[16];
  const float* wv       = (const float*)d_in[17];

  int* knn = (int*)d_ws;                                          // 512 KB
  unsigned short* wT = (unsigned short*)((char*)d_ws + 524288);   // 832 KB bf16
  float* out_res  = (float*)d_out;
  float* out_attn = (float*)d_out + (size_t)BB*MM*DP;

  prep_weights<<<1664, 256, 0, stream>>>(wq, fc1_w, wk, wv, d2_w, g1_w, g2_w, fc2_w, wT);
  knn_kernel<<<BB*MM/NQ, 256, 0, stream>>>(xyz, query, knn);
  fused_mfma<<<BB*MM/2, 256, 0, stream>>>(
      xyz, features, query, fc1_b, fc2_b, d1_w, d1_b, d2_b, g1_b, g2_b,
      wT, knn, out_res, out_attn);
}

// Round 3
// 647.394 us; speedup vs baseline: 1.6299x; 1.1155x over previous
//
#include <hip/hip_runtime.h>
#include <cstdint>
#include <cstddef>

#define BB 4
#define NN 8192
#define MM 2048
#define KK 16
#define DP 128
#define DM 256
#define QROW 131  // 3 + 128 floats per query row
#define NQ 4      // queries per knn block (one per wave)
#define CAP2 384  // per-query candidate capacity
#define CHUNK 2048 // knn xyz LDS chunk (points)

typedef __attribute__((ext_vector_type(8))) short short8;
typedef __attribute__((ext_vector_type(4))) float floatx4;

__device__ __forceinline__ unsigned short f2bf(float x) {
  unsigned u = __float_as_uint(x);
  unsigned r = (u + 0x7FFFu + ((u >> 16) & 1u)) >> 16;   // RNE
  return (unsigned short)r;
}

// Deterministic distance->sortable-key. Same DAG everywhere (LDS-staged or
// global values are bit-identical copies) so threshold comparisons and final
// selection live in one consistent key space.
__device__ __forceinline__ unsigned dkey(float qx, float qy, float qz, float q2,
                                         float xx, float xy, float xz, float x2) {
  float cr = fmaf(qz, xz, fmaf(qy, xy, qx * xx));
  float d  = fmaf(-2.0f, cr, q2 + x2);
  unsigned u = __float_as_uint(d);
  return (u & 0x80000000u) ? ~u : (u | 0x80000000u);  // ascending-sortable
}

// ---------------------------------------------------------------------------
// Kernel 0: weights f32->bf16, transposed to [N][K] (k-contig) back-to-back.
// wk stored NEGATED so fused computes a = (q + pe) + x@(-wk) in one MFMA
// accumulation (caps concurrent accumulators at 64 f32/thread).
// ---------------------------------------------------------------------------
__global__ __launch_bounds__(256) void prep_weights(
    const float* __restrict__ wq, const float* __restrict__ fc1,
    const float* __restrict__ wk, const float* __restrict__ wv,
    const float* __restrict__ d2, const float* __restrict__ g1,
    const float* __restrict__ g2, const float* __restrict__ fc2,
    unsigned short* __restrict__ dst)
{
  long e = (long)blockIdx.x * 256 + threadIdx.x;
  if (e >= 425984) return;
  const float* src; int sh; int Nmat; long off; bool neg = false;
  if (e < 32768)       { src = wq;  sh = 7; Nmat = 256; off = 0; }
  else if (e < 65536)  { src = fc1; sh = 7; Nmat = 256; off = 32768; }
  else if (e < 131072) { src = wk;  sh = 8; Nmat = 256; off = 65536; neg = true; }
  else if (e < 196608) { src = wv;  sh = 8; Nmat = 256; off = 131072; }
  else if (e < 262144) { src = d2;  sh = 8; Nmat = 256; off = 196608; }
  else if (e < 327680) { src = g1;  sh = 8; Nmat = 256; off = 262144; }
  else if (e < 393216) { src = g2;  sh = 8; Nmat = 256; off = 327680; }
  else                 { src = fc2; sh = 8; Nmat = 128; off = 393216; }
  long d = e - off;
  int K = 1 << sh;
  int n = (int)(d >> sh), k = (int)(d & (K - 1));
  float v = src[(long)k * Nmat + n];
  dst[e] = f2bf(neg ? -v : v);
}

// ---------------------------------------------------------------------------
// Kernel 1: exact KNN (k=16), one query per wave, xyz LDS-CHUNKED.
// Per chunk: 256 threads stage 2048 points coalesced (AoS global -> SoA LDS),
// then each wave scans the chunk from LDS (stride-1, conflict-free).
// Threshold T = 16th key of the 1024-point sample (chunk 0, LDS); {u<=T} is
// a provable superset of the true top-16 (subset k-th >= population k-th).
// Stage 3: composite (key,idx) in-register selection (exact top_k ties).
// Fallback (P~1e-8/query): global re-scan, 16 ascending exclusion rounds.
// ---------------------------------------------------------------------------
__global__ __launch_bounds__(256) void knn_kernel(
    const float* __restrict__ xyz, const float* __restrict__ query,
    int* __restrict__ knn_out)
{
  __shared__ float spx[CHUNK], spy[CHUNK], spz[CHUNK];  // 24 KB
  __shared__ unsigned long long cand[NQ][CAP2];         // 12 KB
  __shared__ int s_cnt[NQ];

  const int tid = threadIdx.x;
  const int l = tid & 63, w = tid >> 6;
  const int bmw = blockIdx.x * NQ + w;   // NQ divides 2048 -> same batch
  const int b = bmw >> 11;
  const float* X = xyz + (size_t)b * NN * 3;
  const float* qp = query + (size_t)bmw * QROW;
  const float qx = qp[0], qy = qp[1], qz = qp[2];
  const float q2 = fmaf(qz, qz, fmaf(qy, qy, qx * qx));

  if (tid < NQ) s_cnt[tid] = 0;

  unsigned T = 0xFFFFFFFFu;

  for (int ch = 0; ch < NN / CHUNK; ++ch) {
    __syncthreads();   // prev chunk fully consumed (and s_cnt init visible)
    // ---- stage chunk: coalesced AoS->SoA ----
    {
      const float* src = X + (size_t)ch * CHUNK * 3;
      #pragma unroll
      for (int j = tid; j < CHUNK * 3; j += 256) {
        float v = src[j];
        int p = j / 3, c = j - p * 3;
        if (c == 0) spx[p] = v; else if (c == 1) spy[p] = v; else spz[p] = v;
      }
    }
    __syncthreads();

    if (ch == 0) {
      // ---- threshold from 1024-point sample (points 0..1023, from LDS) ----
      unsigned sk[16];
      #pragma unroll
      for (int i = 0; i < 16; ++i) {
        int n = i * 64 + l;
        float xx = spx[n], xy = spy[n], xz = spz[n];
        float x2 = fmaf(xz, xz, fmaf(xy, xy, xx * xx));
        sk[i] = dkey(qx, qy, qz, q2, xx, xy, xz, x2);
      }
      for (int r = 0; r < KK; ++r) {
        unsigned m = sk[0];
        #pragma unroll
        for (int i = 1; i < 16; ++i) m = sk[i] < m ? sk[i] : m;
        #pragma unroll
        for (int d = 32; d >= 1; d >>= 1) {
          unsigned o = __shfl_xor(m, d, 64);
          m = o < m ? o : m;
        }
        T = m;
        #pragma unroll
        for (int i = 0; i < 16; ++i) if (sk[i] == m) sk[i] = 0xFFFFFFFFu;
      }
    }

    // ---- filtered scan of this chunk from LDS ----
    for (int i = l; i < CHUNK; i += 64) {
      float xx = spx[i], xy = spy[i], xz = spz[i];
      float x2 = fmaf(xz, xz, fmaf(xy, xy, xx * xx));
      unsigned u = dkey(qx, qy, qz, q2, xx, xy, xz, x2);
      if (u <= T) {
        int p = atomicAdd(&s_cnt[w], 1);
        if (p < CAP2) cand[w][p] = ((unsigned long long)u << 32)
                                 | (unsigned)(ch * CHUNK + i);
      }
    }
  }
  const int cnt = s_cnt[w];   // wave-own atomics; no barrier needed

  if (cnt <= CAP2) {
    // ---- in-register selection ----
    unsigned long long v[CAP2 / 64];
    #pragma unroll
    for (int i = 0; i < CAP2/64; ++i) {
      int p = i*64 + l;
      v[i] = (p < cnt) ? cand[w][p] : ~0ull;
    }
    for (int r = 0; r < KK; ++r) {
      unsigned long long m = v[0];
      #pragma unroll
      for (int i = 1; i < CAP2/64; ++i) m = v[i] < m ? v[i] : m;
      #pragma unroll
      for (int d = 32; d >= 1; d >>= 1) {
        unsigned long long o = __shfl_xor(m, d, 64);
        m = o < m ? o : m;
      }
      if (l == 0) knn_out[bmw*KK + r] = (int)(unsigned)(m & 0xffffffffu);
      #pragma unroll
      for (int i = 0; i < CAP2/64; ++i) if (v[i] == m) v[i] = ~0ull;
    }
  } else {
    // ---- fallback (prob ~0): global re-scan, composite exclusion ----
    unsigned long long last = 0;
    for (int r = 0; r < KK; ++r) {
      unsigned long long best = ~0ull;
      for (int n = l; n < NN; n += 64) {
        float xx = X[3*n], xy = X[3*n + 1], xz = X[3*n + 2];
        float x2 = fmaf(xz, xz, fmaf(xy, xy, xx * xx));
        unsigned u = dkey(qx, qy, qz, q2, xx, xy, xz, x2);
        unsigned long long comp = ((unsigned long long)u << 32) | (unsigned)n;
        if (comp > last && comp < best) best = comp;
      }
      #pragma unroll
      for (int d = 32; d >= 1; d >>= 1) {
        unsigned long long o = __shfl_xor(best, d, 64);
        best = o < best ? o : best;
      }
      last = best;
      if (l == 0) knn_out[bmw*KK + r] = (int)(unsigned)(best & 0xffffffffu);
    }
  }
}

// ---------------------------------------------------------------------------
// Balanced MFMA tile-GEMM helper. ks-loop at UNROLL 2: bounds the in-flight
// staging registers (full unroll let the scheduler hoist ~32 global loads ->
// >64 staging VGPRs -> spill; r1/r2 showed 150-600 MB scratch traffic).
// Latency hiding comes from 16 waves/CU TLP instead.
// ---------------------------------------------------------------------------
template<int KT, int RT>
__device__ __forceinline__ void gemm_tiles(
    const unsigned short* aBase, int aStride,
    const unsigned short* __restrict__ bT,
    int lm, int lq, int colBase, int rtBase, floatx4 (&acc)[RT][4])
{
  const unsigned short* aRow = aBase + (rtBase*16 + lm)*aStride + lq*8;
  const unsigned short* bRow = bT + (size_t)(colBase + lm)*(KT*32) + lq*8;
  #pragma unroll 2
  for (int ks = 0; ks < KT; ++ks) {
    short8 af[RT];
    #pragma unroll
    for (int rt = 0; rt < RT; ++rt)
      af[rt] = *(const short8*)&aRow[rt*16*aStride + ks*32];
    short8 bf[4];
    #pragma unroll
    for (int c = 0; c < 4; ++c)
      bf[c] = *(const short8*)&bRow[(size_t)c*16*(KT*32) + ks*32];
    #pragma unroll
    for (int rt = 0; rt < RT; ++rt)
      #pragma unroll
      for (int c = 0; c < 4; ++c)
        acc[rt][c] = __builtin_amdgcn_mfma_f32_16x16x32_bf16(af[rt], bf[c], acc[rt][c], 0, 0, 0);
  }
}

// ---------------------------------------------------------------------------
// Kernel 2: fused block, 2 queries (32 rows) per 256-thread WG, 4 blocks/CU.
// Concurrent MFMA accumulators capped at 64 f32/thread (pe+vpe, vpe+a,
// vpe+h, vpe+lg); staging bounded by unroll-2 -> target zero scratch.
// ---------------------------------------------------------------------------
__global__ __launch_bounds__(256, 4) void fused_mfma(
    const float* __restrict__ xyz, const float* __restrict__ features,
    const float* __restrict__ query,
    const float* __restrict__ fc1_b, const float* __restrict__ fc2_b,
    const float* __restrict__ d1_w,  const float* __restrict__ d1_b,
    const float* __restrict__ d2_b,
    const float* __restrict__ g1_b,  const float* __restrict__ g2_b,
    const unsigned short* __restrict__ wT,
    const int* __restrict__ knn_idx,
    float* __restrict__ out_res, float* __restrict__ out_attn)
{
  const unsigned short* wq_t  = wT;
  const unsigned short* fc1_t = wT + 32768;
  const unsigned short* wkN_t = wT + 65536;    // negated
  const unsigned short* wv_t  = wT + 131072;
  const unsigned short* d2_t  = wT + 196608;
  const unsigned short* g1_t  = wT + 262144;
  const unsigned short* g2_t  = wT + 327680;
  const unsigned short* fc2_t = wT + 393216;

  __shared__ alignas(16) unsigned short bufA[32*264];  // feat(136) / h1 / a / rm
  __shared__ alignas(16) unsigned short bufB[32*264];  // x / h
  __shared__ alignas(16) unsigned short s_qf[16*136];  // query_f bf16 (rows 0..1)
  __shared__ alignas(16) float s_q[2*256];             // q projection (f32)
  __shared__ float s_delta[32][4];
  __shared__ int   s_idx[32];

  const int tid = threadIdx.x;
  const int l  = tid & 63, w = tid >> 6;
  const int lm = l & 15,  lq = l >> 4;
  const int colBase = w * 64;
  const int bm0 = blockIdx.x << 1;
  const int b   = bm0 >> 11;

  // ---- Phase 0: indices, delta, query_f, feature gather ----
  if (tid < 32) {
    int q = tid >> 4, n = tid & 15;
    int idx = knn_idx[(bm0 + q)*KK + n];
    s_idx[tid] = idx;
    const float* qp = query + (size_t)(bm0 + q) * QROW;
    const float* xp = xyz + ((size_t)b*NN + idx)*3;
    s_delta[tid][0] = qp[0] - xp[0];
    s_delta[tid][1] = qp[1] - xp[1];
    s_delta[tid][2] = qp[2] - xp[2];
  }
  if (tid < 128) {
    int e = tid * 2;                    // 256 elems: rows 0..1 x 128 cols
    int q = e >> 7, c = e & 127;
    const float* qp = query + (size_t)(bm0 + q)*QROW + 3 + c;
    unsigned v = ((unsigned)f2bf(qp[1]) << 16) | f2bf(qp[0]);
    *(unsigned*)&s_qf[q*136 + c] = v;
  }
  __syncthreads();
  {
    int r = tid >> 3, c0 = (tid & 7) * 16;
    const float4* fp4 = (const float4*)(features + ((size_t)b*NN + s_idx[r])*DP + c0);
    unsigned short* dst = &bufA[r*136 + c0];
    #pragma unroll
    for (int i = 0; i < 4; ++i) {
      float4 v4 = fp4[i];
      *(unsigned*)&dst[i*4]     = ((unsigned)f2bf(v4.y) << 16) | f2bf(v4.x);
      *(unsigned*)&dst[i*4 + 2] = ((unsigned)f2bf(v4.w) << 16) | f2bf(v4.z);
    }
  }
  __syncthreads();

  const floatx4 zero4 = {0.f, 0.f, 0.f, 0.f};

  // ---- Phase 1: x = feat @ fc1 + b  -> bufB ;  q = qf @ wq -> s_q ----
  {
    floatx4 acc[2][4];
    #pragma unroll
    for (int rt = 0; rt < 2; ++rt)
      #pragma unroll
      for (int c = 0; c < 4; ++c) acc[rt][c] = zero4;
    gemm_tiles<4,2>(bufA, 136, fc1_t, lm, lq, colBase, 0, acc);
    #pragma unroll
    for (int c = 0; c < 4; ++c) {
      float bias = fc1_b[colBase + c*16 + lm];
      #pragma unroll
      for (int rt = 0; rt < 2; ++rt)
        #pragma unroll
        for (int r = 0; r < 4; ++r)
          bufB[(rt*16 + lq*4 + r)*264 + colBase + c*16 + lm] = f2bf(acc[rt][c][r] + bias);
    }
  }
  {
    floatx4 qa[1][4];
    #pragma unroll
    for (int c = 0; c < 4; ++c) qa[0][c] = zero4;
    gemm_tiles<4,1>(s_qf, 136, wq_t, lm, lq, colBase, 0, qa);
    if (lq == 0) {
      #pragma unroll
      for (int c = 0; c < 4; ++c)
        #pragma unroll
        for (int r = 0; r < 2; ++r)
          s_q[r*256 + colBase + c*16 + lm] = qa[0][c][r];   // row r == query r
    }
  }
  __syncthreads();   // x visible; bufA(feat) dead

  // ---- Phase 2: h1 = relu(delta @ d1 + b) -> bufA (VALU, tiny K=3) ----
  {
    int c = tid;
    float w0 = d1_w[c], w1 = d1_w[256 + c], w2 = d1_w[512 + c], bb = d1_b[c];
    #pragma unroll 4
    for (int r = 0; r < 32; ++r) {
      float v = fmaf(s_delta[r][2], w2, fmaf(s_delta[r][1], w1,
                fmaf(s_delta[r][0], w0, bb)));
      bufA[r*264 + c] = f2bf(v > 0.f ? v : 0.f);
    }
  }
  __syncthreads();   // h1 visible

  // ---- Phase 3: pe = h1 @ d2 + b (regs; acc set #1) ----
  floatx4 pe[2][4];
  #pragma unroll
  for (int rt = 0; rt < 2; ++rt)
    #pragma unroll
    for (int c = 0; c < 4; ++c) pe[rt][c] = zero4;
  gemm_tiles<8,2>(bufA, 264, d2_t, lm, lq, colBase, 0, pe);
  #pragma unroll
  for (int c = 0; c < 4; ++c) {
    float bias = d2_b[colBase + c*16 + lm];
    #pragma unroll
    for (int rt = 0; rt < 2; ++rt)
      #pragma unroll
      for (int r = 0; r < 4; ++r) pe[rt][c][r] += bias;
  }

  // ---- Phase 4: vpe = x @ wv + pe (acc set #2 initialized from pe) ----
  floatx4 vpe[2][4];
  #pragma unroll
  for (int rt = 0; rt < 2; ++rt)
    #pragma unroll
    for (int c = 0; c < 4; ++c) vpe[rt][c] = pe[rt][c];
  gemm_tiles<8,2>(bufB, 264, wv_t, lm, lq, colBase, 0, vpe);
  __syncthreads();   // all waves done reading bufA(h1); a-writes may begin

  // ---- Phase 5: a = (q + pe) + x @ (-wk) -> bufA ; pe dies in the init ----
  {
    floatx4 acc[2][4];
    #pragma unroll
    for (int rt = 0; rt < 2; ++rt)
      #pragma unroll
      for (int c = 0; c < 4; ++c) {
        float qv = s_q[rt*256 + colBase + c*16 + lm];
        #pragma unroll
        for (int r = 0; r < 4; ++r) acc[rt][c][r] = qv + pe[rt][c][r];
      }
    gemm_tiles<8,2>(bufB, 264, wkN_t, lm, lq, colBase, 0, acc);
    #pragma unroll
    for (int rt = 0; rt < 2; ++rt)
      #pragma unroll
      for (int c = 0; c < 4; ++c)
        #pragma unroll
        for (int r = 0; r < 4; ++r)
          bufA[(rt*16 + lq*4 + r)*264 + colBase + c*16 + lm] = f2bf(acc[rt][c][r]);
  }
  __syncthreads();   // a visible; bufB(x) dead

  // ---- Phase 6: h = relu(a @ g1 + b) -> bufB ----
  {
    floatx4 h[2][4];
    #pragma unroll
    for (int rt = 0; rt < 2; ++rt)
      #pragma unroll
      for (int c = 0; c < 4; ++c) h[rt][c] = zero4;
    gemm_tiles<8,2>(bufA, 264, g1_t, lm, lq, colBase, 0, h);
    #pragma unroll
    for (int c = 0; c < 4; ++c) {
      float bias = g1_b[colBase + c*16 + lm];
      #pragma unroll
      for (int rt = 0; rt < 2; ++rt)
        #pragma unroll
        for (int r = 0; r < 4; ++r) {
          float v = h[rt][c][r] + bias;
          bufB[(rt*16 + lq*4 + r)*264 + colBase + c*16 + lm] = f2bf(v > 0.f ? v : 0.f);
        }
    }
  }
  __syncthreads();   // h visible; bufA(a) dead -> reuse as s_rm

  // ---- Phase 7/8: lg = h @ g2 + b (both rt at once), softmax over
  //      neighbors, nontemporal attn store, rm = sum_n attn * vpe ----
  unsigned short* s_rm = bufA;   // [16][264], rows 0..1 valid
  {
    floatx4 lg[2][4];
    #pragma unroll
    for (int rt = 0; rt < 2; ++rt)
      #pragma unroll
      for (int c = 0; c < 4; ++c) lg[rt][c] = zero4;
    gemm_tiles<8,2>(bufB, 264, g2_t, lm, lq, colBase, 0, lg);
    #pragma unroll
    for (int rt = 0; rt < 2; ++rt) {
      #pragma unroll
      for (int c = 0; c < 4; ++c) {
        float bias = g2_b[colBase + c*16 + lm];
        float v[4];
        float mx = -INFINITY;
        #pragma unroll
        for (int r = 0; r < 4; ++r) {
          v[r] = (lg[rt][c][r] + bias) * 0.0625f;
          mx = fmaxf(mx, v[r]);
        }
        mx = fmaxf(mx, __shfl_xor(mx, 16, 64));
        mx = fmaxf(mx, __shfl_xor(mx, 32, 64));
        float s = 0.f;
        #pragma unroll
        for (int r = 0; r < 4; ++r) { v[r] = __expf(v[r] - mx); s += v[r]; }
        s += __shfl_xor(s, 16, 64);
        s += __shfl_xor(s, 32, 64);
        float inv = 1.0f / s;
        float rm = 0.f;
        size_t abase = ((size_t)(bm0 + rt)*KK)*DM + colBase + c*16 + lm;
        #pragma unroll
        for (int r = 0; r < 4; ++r) {
          float at = v[r] * inv;
          __builtin_nontemporal_store(at, &out_attn[abase + (size_t)(lq*4 + r)*DM]);
          rm = fmaf(at, vpe[rt][c][r], rm);
        }
        rm += __shfl_xor(rm, 16, 64);
        rm += __shfl_xor(rm, 32, 64);
        if (lq == 0) s_rm[rt*264 + colBase + c*16 + lm] = f2bf(rm);
      }
    }
  }
  __syncthreads();

  // ---- Phase 9: res = rm @ fc2 + b + query_f ----
  {
    floatx4 acc[2];
    acc[0] = zero4; acc[1] = zero4;
    #pragma unroll 2
    for (int ks = 0; ks < 8; ++ks) {
      short8 af = *(const short8*)&s_rm[lm*264 + ks*32 + lq*8];
      #pragma unroll
      for (int c = 0; c < 2; ++c) {
        int col = (w*2 + c)*16 + lm;
        short8 bf = *(const short8*)&fc2_t[(size_t)col*256 + ks*32 + lq*8];
        acc[c] = __builtin_amdgcn_mfma_f32_16x16x32_bf16(af, bf, acc[c], 0, 0, 0);
      }
    }
    if (lq == 0) {
      #pragma unroll
      for (int c = 0; c < 2; ++c) {
        int col = (w*2 + c)*16 + lm;
        float bias = fc2_b[col];
        #pragma unroll
        for (int r = 0; r < 2; ++r) {
          float res = acc[c][r] + bias + query[(size_t)(bm0 + r)*QROW + 3 + col];
          __builtin_nontemporal_store(res, &out_res[(size_t)(bm0 + r)*DP + col]);
        }
      }
    }
  }
}

extern "C" void kernel_launch(void* const* d_in, const int* in_sizes, int n_in,
                              void* d_out, int out_size, void* d_ws, size_t ws_size,
                              hipStream_t stream) {
  const float* xyz      = (const float*)d_in[0];
  const float* features = (const float*)d_in[1];
  const float* query    = (const float*)d_in[2];
  const float* fc1_w    = (const float*)d_in[3];
  const float* fc1_b    = (const float*)d_in[4];
  const float* fc2_w    = (const float*)d_in[5];
  const float* fc2_b    = (const float*)d_in[6];
  const float* d1_w     = (const float*)d_in[7];
  const float* d1_b     = (const float*)d_in[8];
  const float* d2_w     = (const float*)d_in[9];
  const float* d2_b     = (const float*)d_in[10];
  const float* g1_w     = (const float*)d_in[11];
  const float* g1_b     = (const float*)d_in[12];
  const float* g2_w     = (const float*)d_in[13];
  const float* g2_b     = (const float*)d_in[14];
  const float* wq       = (const float*)d_in[15];
  const float* wk       = (const float*)d_in[16];
  const float* wv       = (const float*)d_in[17];

  int* knn = (int*)d_ws;                                          // 512 KB
  unsigned short* wT = (unsigned short*)((char*)d_ws + 524288);   // 832 KB bf16
  float* out_res  = (float*)d_out;
  float* out_attn = (float*)d_out + (size_t)BB*MM*DP;

  prep_weights<<<1664, 256, 0, stream>>>(wq, fc1_w, wk, wv, d2_w, g1_w, g2_w, fc2_w, wT);
  knn_kernel<<<BB*MM/NQ, 256, 0, stream>>>(xyz, query, knn);
  fused_mfma<<<BB*MM/2, 256, 0, stream>>>(
      xyz, features, query, fc1_b, fc2_b, d1_w, d1_b, d2_b, g1_b, g2_b,
      wT, knn, out_res, out_attn);
}

// Round 4
// 552.659 us; speedup vs baseline: 1.9093x; 1.1714x over previous
//
#include <hip/hip_runtime.h>
#include <cstdint>
#include <cstddef>

#define BB 4
#define NN 8192
#define MM 2048
#define KK 16
#define DP 128
#define DM 256
#define QROW 131  // 3 + 128 floats per query row
#define KNQ 2     // queries per knn block (one per wave)
#define CAP2 384  // per-query candidate capacity

typedef __attribute__((ext_vector_type(8))) short short8;
typedef __attribute__((ext_vector_type(4))) float floatx4;

__device__ __forceinline__ unsigned short f2bf(float x) {
  unsigned u = __float_as_uint(x);
  unsigned r = (u + 0x7FFFu + ((u >> 16) & 1u)) >> 16;   // RNE
  return (unsigned short)r;
}

// Deterministic distance->sortable-key. Same DAG everywhere so threshold
// comparisons and final selection live in one consistent key space.
__device__ __forceinline__ unsigned dkey(float qx, float qy, float qz, float q2,
                                         float xx, float xy, float xz, float x2) {
  float cr = fmaf(qz, xz, fmaf(qy, xy, qx * xx));
  float d  = fmaf(-2.0f, cr, q2 + x2);
  unsigned u = __float_as_uint(d);
  return (u & 0x80000000u) ? ~u : (u | 0x80000000u);  // ascending-sortable
}

// ---------------------------------------------------------------------------
// Kernel 0: weights f32->bf16, transposed to [N][K] (k-contig) back-to-back.
// wk stored NEGATED so fused computes a = (q + pe) + x@(-wk) in one MFMA
// accumulation (bounds concurrent accumulators; pe dies into the a-init).
// ---------------------------------------------------------------------------
__global__ __launch_bounds__(256) void prep_weights(
    const float* __restrict__ wq, const float* __restrict__ fc1,
    const float* __restrict__ wk, const float* __restrict__ wv,
    const float* __restrict__ d2, const float* __restrict__ g1,
    const float* __restrict__ g2, const float* __restrict__ fc2,
    unsigned short* __restrict__ dst)
{
  long e = (long)blockIdx.x * 256 + threadIdx.x;
  if (e >= 425984) return;
  const float* src; int sh; int Nmat; long off; bool neg = false;
  if (e < 32768)       { src = wq;  sh = 7; Nmat = 256; off = 0; }
  else if (e < 65536)  { src = fc1; sh = 7; Nmat = 256; off = 32768; }
  else if (e < 131072) { src = wk;  sh = 8; Nmat = 256; off = 65536; neg = true; }
  else if (e < 196608) { src = wv;  sh = 8; Nmat = 256; off = 131072; }
  else if (e < 262144) { src = d2;  sh = 8; Nmat = 256; off = 196608; }
  else if (e < 327680) { src = g1;  sh = 8; Nmat = 256; off = 262144; }
  else if (e < 393216) { src = g2;  sh = 8; Nmat = 256; off = 327680; }
  else                 { src = fc2; sh = 8; Nmat = 128; off = 393216; }
  long d = e - off;
  int K = 1 << sh;
  int n = (int)(d >> sh), k = (int)(d & (K - 1));
  float v = src[(long)k * Nmat + n];
  dst[e] = f2bf(neg ? -v : v);
}

// ---------------------------------------------------------------------------
// Kernel 1: exact KNN (k=16). ONE QUERY PER WAVE, 2 waves/block, ZERO
// barriers. 4096 blocks -> 16 blocks/CU -> 32 waves/CU (full occupancy);
// xyz (96 KB/batch) is L2-resident and shared by all waves on an XCD.
// Stage 1: 1024-point sample -> threshold T (16th key; subset k-th >=
//   population k-th, so {u<=T} is a superset of the true top-16).
// Stage 2: filtered global scan (E[cand]~130, cap 384).
// Stage 3: composite (key,idx) in-register selection (exact top_k ties).
// Fallback (P~0): global re-scan, 16 ascending exclusion rounds.
// ---------------------------------------------------------------------------
__global__ __launch_bounds__(128) void knn_kernel(
    const float* __restrict__ xyz, const float* __restrict__ query,
    int* __restrict__ knn_out)
{
  __shared__ unsigned long long cand[KNQ][CAP2];   // 6 KB
  __shared__ int s_cnt[KNQ];

  const int tid = threadIdx.x;
  const int l = tid & 63, w = tid >> 6;
  const int bmw = blockIdx.x * KNQ + w;
  const int b = bmw >> 11;
  const float* X = xyz + (size_t)b * NN * 3;
  const float* qp = query + (size_t)bmw * QROW;
  const float qx = qp[0], qy = qp[1], qz = qp[2];
  const float q2 = fmaf(qz, qz, fmaf(qy, qy, qx * qx));

  if (l == 0) s_cnt[w] = 0;   // same-wave DS ordering; no barrier needed

  // ---- Stage 1: sample 1024 points, extract threshold ----
  unsigned sk[16];
  #pragma unroll
  for (int i = 0; i < 16; ++i) {
    int n = i * 64 + l;
    float xx = X[3*n], xy = X[3*n + 1], xz = X[3*n + 2];
    float x2 = fmaf(xz, xz, fmaf(xy, xy, xx * xx));
    sk[i] = dkey(qx, qy, qz, q2, xx, xy, xz, x2);
  }
  unsigned T = 0xFFFFFFFFu;
  for (int r = 0; r < KK; ++r) {
    unsigned m = sk[0];
    #pragma unroll
    for (int i = 1; i < 16; ++i) m = sk[i] < m ? sk[i] : m;
    #pragma unroll
    for (int d = 32; d >= 1; d >>= 1) {
      unsigned o = __shfl_xor(m, d, 64);
      m = o < m ? o : m;
    }
    T = m;
    #pragma unroll
    for (int i = 0; i < 16; ++i) if (sk[i] == m) sk[i] = 0xFFFFFFFFu;
  }

  // ---- Stage 2: filtered full scan (L2-resident xyz) ----
  for (int n = l; n < NN; n += 64) {
    float xx = X[3*n], xy = X[3*n + 1], xz = X[3*n + 2];
    float x2 = fmaf(xz, xz, fmaf(xy, xy, xx * xx));
    unsigned u = dkey(qx, qy, qz, q2, xx, xy, xz, x2);
    if (u <= T) {
      int p = atomicAdd(&s_cnt[w], 1);
      if (p < CAP2) cand[w][p] = ((unsigned long long)u << 32) | (unsigned)n;
    }
  }
  const int cnt = s_cnt[w];   // wave-own atomics; ordered per-wave

  if (cnt <= CAP2) {
    // ---- Stage 3: in-register selection ----
    unsigned long long v[CAP2 / 64];
    #pragma unroll
    for (int i = 0; i < CAP2/64; ++i) {
      int p = i*64 + l;
      v[i] = (p < cnt) ? cand[w][p] : ~0ull;
    }
    for (int r = 0; r < KK; ++r) {
      unsigned long long m = v[0];
      #pragma unroll
      for (int i = 1; i < CAP2/64; ++i) m = v[i] < m ? v[i] : m;
      #pragma unroll
      for (int d = 32; d >= 1; d >>= 1) {
        unsigned long long o = __shfl_xor(m, d, 64);
        m = o < m ? o : m;
      }
      if (l == 0) knn_out[bmw*KK + r] = (int)(unsigned)(m & 0xffffffffu);
      #pragma unroll
      for (int i = 0; i < CAP2/64; ++i) if (v[i] == m) v[i] = ~0ull;
    }
  } else {
    // ---- Fallback (prob ~0): 16 ascending rounds, composite exclusion ----
    unsigned long long last = 0;
    for (int r = 0; r < KK; ++r) {
      unsigned long long best = ~0ull;
      for (int n = l; n < NN; n += 64) {
        float xx = X[3*n], xy = X[3*n + 1], xz = X[3*n + 2];
        float x2 = fmaf(xz, xz, fmaf(xy, xy, xx * xx));
        unsigned u = dkey(qx, qy, qz, q2, xx, xy, xz, x2);
        unsigned long long comp = ((unsigned long long)u << 32) | (unsigned)n;
        if (comp > last && comp < best) best = comp;
      }
      #pragma unroll
      for (int d = 32; d >= 1; d >>= 1) {
        unsigned long long o = __shfl_xor(best, d, 64);
        best = o < best ? o : best;
      }
      last = best;
      if (l == 0) knn_out[bmw*KK + r] = (int)(unsigned)(best & 0xffffffffu);
    }
  }
}

// ---------------------------------------------------------------------------
// Balanced MFMA tile-GEMM helper. ks-loop at UNROLL 2 bounds in-flight
// staging registers (full unroll -> scheduler hoists ~32 global loads ->
// spill; proven r2->r3: WRITE 352->185 MB).
// ---------------------------------------------------------------------------
template<int KT, int RT>
__device__ __forceinline__ void gemm_tiles(
    const unsigned short* aBase, int aStride,
    const unsigned short* __restrict__ bT,
    int lm, int lq, int colBase, int rtBase, floatx4 (&acc)[RT][4])
{
  const unsigned short* aRow = aBase + (rtBase*16 + lm)*aStride + lq*8;
  const unsigned short* bRow = bT + (size_t)(colBase + lm)*(KT*32) + lq*8;
  #pragma unroll 2
  for (int ks = 0; ks < KT; ++ks) {
    short8 af[RT];
    #pragma unroll
    for (int rt = 0; rt < RT; ++rt)
      af[rt] = *(const short8*)&aRow[rt*16*aStride + ks*32];
    short8 bf[4];
    #pragma unroll
    for (int c = 0; c < 4; ++c)
      bf[c] = *(const short8*)&bRow[(size_t)c*16*(KT*32) + ks*32];
    #pragma unroll
    for (int rt = 0; rt < RT; ++rt)
      #pragma unroll
      for (int c = 0; c < 4; ++c)
        acc[rt][c] = __builtin_amdgcn_mfma_f32_16x16x32_bf16(af[rt], bf[c], acc[rt][c], 0, 0, 0);
  }
}

// ---------------------------------------------------------------------------
// Kernel 2: fused block, 4 queries (64 rows) per 256-thread WG, 2 blocks/CU.
// r0's structure (empirically fastest: most MFMA work per barrier, best
// B-load amortization) + register discipline so RT=4 runs WITHOUT the
// ~345 MB scratch r0 paid: launch_bounds(256,2) -> 256-VGPR budget; peak
// live = 128 acc (pe+vpe | vpe+a | vpe+h | vpe+lg) + ~64 staging + misc.
// ---------------------------------------------------------------------------
__global__ __launch_bounds__(256, 2) void fused_mfma(
    const float* __restrict__ xyz, const float* __restrict__ features,
    const float* __restrict__ query,
    const float* __restrict__ fc1_b, const float* __restrict__ fc2_b,
    const float* __restrict__ d1_w,  const float* __restrict__ d1_b,
    const float* __restrict__ d2_b,
    const float* __restrict__ g1_b,  const float* __restrict__ g2_b,
    const unsigned short* __restrict__ wT,
    const int* __restrict__ knn_idx,
    float* __restrict__ out_res, float* __restrict__ out_attn)
{
  const unsigned short* wq_t  = wT;
  const unsigned short* fc1_t = wT + 32768;
  const unsigned short* wkN_t = wT + 65536;    // negated
  const unsigned short* wv_t  = wT + 131072;
  const unsigned short* d2_t  = wT + 196608;
  const unsigned short* g1_t  = wT + 262144;
  const unsigned short* g2_t  = wT + 327680;
  const unsigned short* fc2_t = wT + 393216;

  __shared__ alignas(16) unsigned short bufA[64*264];  // feat(136) / h1 / a / rm
  __shared__ alignas(16) unsigned short bufB[64*264];  // x / h
  __shared__ alignas(16) unsigned short s_qf[16*136];  // query_f bf16 (rows 0..3)
  __shared__ alignas(16) float s_q[4*256];             // q projection (f32)
  __shared__ float s_delta[64][4];
  __shared__ int   s_idx[64];

  const int tid = threadIdx.x;
  const int l  = tid & 63, w = tid >> 6;
  const int lm = l & 15,  lq = l >> 4;
  const int colBase = w * 64;
  const int bm0 = blockIdx.x << 2;
  const int b   = bm0 >> 11;

  // ---- Phase 0: indices, delta, query_f, feature gather ----
  if (tid < 64) {
    int q = tid >> 4, n = tid & 15;
    int idx = knn_idx[(bm0 + q)*KK + n];
    s_idx[tid] = idx;
    const float* qp = query + (size_t)(bm0 + q) * QROW;
    const float* xp = xyz + ((size_t)b*NN + idx)*3;
    s_delta[tid][0] = qp[0] - xp[0];
    s_delta[tid][1] = qp[1] - xp[1];
    s_delta[tid][2] = qp[2] - xp[2];
  }
  {
    int e = tid * 2;                    // 512 elems: rows 0..3 x 128 cols
    int q = e >> 7, c = e & 127;
    const float* qp = query + (size_t)(bm0 + q)*QROW + 3 + c;
    unsigned v = ((unsigned)f2bf(qp[1]) << 16) | f2bf(qp[0]);
    *(unsigned*)&s_qf[q*136 + c] = v;
  }
  __syncthreads();
  {
    int r = tid >> 2, c0 = (tid & 3) * 32;
    const float4* fp4 = (const float4*)(features + ((size_t)b*NN + s_idx[r])*DP + c0);
    unsigned short* dst = &bufA[r*136 + c0];
    #pragma unroll
    for (int i = 0; i < 8; ++i) {
      float4 v4 = fp4[i];
      *(unsigned*)&dst[i*4]     = ((unsigned)f2bf(v4.y) << 16) | f2bf(v4.x);
      *(unsigned*)&dst[i*4 + 2] = ((unsigned)f2bf(v4.w) << 16) | f2bf(v4.z);
    }
  }
  __syncthreads();

  const floatx4 zero4 = {0.f, 0.f, 0.f, 0.f};

  // ---- Phase 1: x = feat @ fc1 + b  -> bufB ;  q = qf @ wq -> s_q ----
  {
    floatx4 acc[4][4];
    #pragma unroll
    for (int rt = 0; rt < 4; ++rt)
      #pragma unroll
      for (int c = 0; c < 4; ++c) acc[rt][c] = zero4;
    gemm_tiles<4,4>(bufA, 136, fc1_t, lm, lq, colBase, 0, acc);
    #pragma unroll
    for (int c = 0; c < 4; ++c) {
      float bias = fc1_b[colBase + c*16 + lm];
      #pragma unroll
      for (int rt = 0; rt < 4; ++rt)
        #pragma unroll
        for (int r = 0; r < 4; ++r)
          bufB[(rt*16 + lq*4 + r)*264 + colBase + c*16 + lm] = f2bf(acc[rt][c][r] + bias);
    }
  }
  {
    floatx4 qa[1][4];
    #pragma unroll
    for (int c = 0; c < 4; ++c) qa[0][c] = zero4;
    gemm_tiles<4,1>(s_qf, 136, wq_t, lm, lq, colBase, 0, qa);
    if (lq == 0) {
      #pragma unroll
      for (int c = 0; c < 4; ++c)
        #pragma unroll
        for (int r = 0; r < 4; ++r)
          s_q[r*256 + colBase + c*16 + lm] = qa[0][c][r];   // row r == query r
    }
  }
  __syncthreads();   // x visible; bufA(feat) dead

  // ---- Phase 2: h1 = relu(delta @ d1 + b) -> bufA (VALU, tiny K=3) ----
  {
    int c = tid;
    float w0 = d1_w[c], w1 = d1_w[256 + c], w2 = d1_w[512 + c], bb = d1_b[c];
    #pragma unroll 4
    for (int r = 0; r < 64; ++r) {
      float v = fmaf(s_delta[r][2], w2, fmaf(s_delta[r][1], w1,
                fmaf(s_delta[r][0], w0, bb)));
      bufA[r*264 + c] = f2bf(v > 0.f ? v : 0.f);
    }
  }
  __syncthreads();   // h1 visible

  // ---- Phase 3: pe = h1 @ d2 + b (regs; acc set #1) ----
  floatx4 pe[4][4];
  #pragma unroll
  for (int rt = 0; rt < 4; ++rt)
    #pragma unroll
    for (int c = 0; c < 4; ++c) pe[rt][c] = zero4;
  gemm_tiles<8,4>(bufA, 264, d2_t, lm, lq, colBase, 0, pe);
  #pragma unroll
  for (int c = 0; c < 4; ++c) {
    float bias = d2_b[colBase + c*16 + lm];
    #pragma unroll
    for (int rt = 0; rt < 4; ++rt)
      #pragma unroll
      for (int r = 0; r < 4; ++r) pe[rt][c][r] += bias;
  }

  // ---- Phase 4: vpe = x @ wv + pe (acc set #2 initialized from pe) ----
  floatx4 vpe[4][4];
  #pragma unroll
  for (int rt = 0; rt < 4; ++rt)
    #pragma unroll
    for (int c = 0; c < 4; ++c) vpe[rt][c] = pe[rt][c];
  gemm_tiles<8,4>(bufB, 264, wv_t, lm, lq, colBase, 0, vpe);
  __syncthreads();   // all waves done reading bufA(h1); a-writes may begin

  // ---- Phase 5: a = (q + pe) + x @ (-wk) -> bufA ; pe dies in the init ----
  {
    floatx4 acc[4][4];
    #pragma unroll
    for (int rt = 0; rt < 4; ++rt)
      #pragma unroll
      for (int c = 0; c < 4; ++c) {
        float qv = s_q[rt*256 + colBase + c*16 + lm];
        #pragma unroll
        for (int r = 0; r < 4; ++r) acc[rt][c][r] = qv + pe[rt][c][r];
      }
    gemm_tiles<8,4>(bufB, 264, wkN_t, lm, lq, colBase, 0, acc);
    #pragma unroll
    for (int rt = 0; rt < 4; ++rt)
      #pragma unroll
      for (int c = 0; c < 4; ++c)
        #pragma unroll
        for (int r = 0; r < 4; ++r)
          bufA[(rt*16 + lq*4 + r)*264 + colBase + c*16 + lm] = f2bf(acc[rt][c][r]);
  }
  __syncthreads();   // a visible; bufB(x) dead

  // ---- Phase 6: h = relu(a @ g1 + b) -> bufB ----
  {
    floatx4 h[4][4];
    #pragma unroll
    for (int rt = 0; rt < 4; ++rt)
      #pragma unroll
      for (int c = 0; c < 4; ++c) h[rt][c] = zero4;
    gemm_tiles<8,4>(bufA, 264, g1_t, lm, lq, colBase, 0, h);
    #pragma unroll
    for (int c = 0; c < 4; ++c) {
      float bias = g1_b[colBase + c*16 + lm];
      #pragma unroll
      for (int rt = 0; rt < 4; ++rt)
        #pragma unroll
        for (int r = 0; r < 4; ++r) {
          float v = h[rt][c][r] + bias;
          bufB[(rt*16 + lq*4 + r)*264 + colBase + c*16 + lm] = f2bf(v > 0.f ? v : 0.f);
        }
    }
  }
  __syncthreads();   // h visible; bufA(a) dead -> reuse as s_rm

  // ---- Phase 7/8: lg = h @ g2 + b (all rt in ONE gemm: B loaded once),
  //      softmax over neighbors, NT attn store, rm = sum_n attn * vpe ----
  unsigned short* s_rm = bufA;   // [16][264], rows 0..3 valid
  {
    floatx4 lg[4][4];
    #pragma unroll
    for (int rt = 0; rt < 4; ++rt)
      #pragma unroll
      for (int c = 0; c < 4; ++c) lg[rt][c] = zero4;
    gemm_tiles<8,4>(bufB, 264, g2_t, lm, lq, colBase, 0, lg);
    #pragma unroll
    for (int rt = 0; rt < 4; ++rt) {
      #pragma unroll
      for (int c = 0; c < 4; ++c) {
        float bias = g2_b[colBase + c*16 + lm];
        float v[4];
        float mx = -INFINITY;
        #pragma unroll
        for (int r = 0; r < 4; ++r) {
          v[r] = (lg[rt][c][r] + bias) * 0.0625f;
          mx = fmaxf(mx, v[r]);
        }
        mx = fmaxf(mx, __shfl_xor(mx, 16, 64));
        mx = fmaxf(mx, __shfl_xor(mx, 32, 64));
        float s = 0.f;
        #pragma unroll
        for (int r = 0; r < 4; ++r) { v[r] = __expf(v[r] - mx); s += v[r]; }
        s += __shfl_xor(s, 16, 64);
        s += __shfl_xor(s, 32, 64);
        float inv = 1.0f / s;
        float rm = 0.f;
        size_t abase = ((size_t)(bm0 + rt)*KK)*DM + colBase + c*16 + lm;
        #pragma unroll
        for (int r = 0; r < 4; ++r) {
          float at = v[r] * inv;
          __builtin_nontemporal_store(at, &out_attn[abase + (size_t)(lq*4 + r)*DM]);
          rm = fmaf(at, vpe[rt][c][r], rm);
        }
        rm += __shfl_xor(rm, 16, 64);
        rm += __shfl_xor(rm, 32, 64);
        if (lq == 0) s_rm[rt*264 + colBase + c*16 + lm] = f2bf(rm);
      }
    }
  }
  __syncthreads();

  // ---- Phase 9: res = rm @ fc2 + b + query_f ----
  {
    floatx4 acc[2];
    acc[0] = zero4; acc[1] = zero4;
    #pragma unroll 2
    for (int ks = 0; ks < 8; ++ks) {
      short8 af = *(const short8*)&s_rm[lm*264 + ks*32 + lq*8];
      #pragma unroll
      for (int c = 0; c < 2; ++c) {
        int col = (w*2 + c)*16 + lm;
        short8 bf = *(const short8*)&fc2_t[(size_t)col*256 + ks*32 + lq*8];
        acc[c] = __builtin_amdgcn_mfma_f32_16x16x32_bf16(af, bf, acc[c], 0, 0, 0);
      }
    }
    if (lq == 0) {
      #pragma unroll
      for (int c = 0; c < 2; ++c) {
        int col = (w*2 + c)*16 + lm;
        float bias = fc2_b[col];
        #pragma unroll
        for (int r = 0; r < 4; ++r) {
          float res = acc[c][r] + bias + query[(size_t)(bm0 + r)*QROW + 3 + col];
          __builtin_nontemporal_store(res, &out_res[(size_t)(bm0 + r)*DP + col]);
        }
      }
    }
  }
}

extern "C" void kernel_launch(void* const* d_in, const int* in_sizes, int n_in,
                              void* d_out, int out_size, void* d_ws, size_t ws_size,
                              hipStream_t stream) {
  const float* xyz      = (const float*)d_in[0];
  const float* features = (const float*)d_in[1];
  const float* query    = (const float*)d_in[2];
  const float* fc1_w    = (const float*)d_in[3];
  const float* fc1_b    = (const float*)d_in[4];
  const float* fc2_w    = (const float*)d_in[5];
  const float* fc2_b    = (const float*)d_in[6];
  const float* d1_w     = (const float*)d_in[7];
  const float* d1_b     = (const float*)d_in[8];
  const float* d2_w     = (const float*)d_in[9];
  const float* d2_b     = (const float*)d_in[10];
  const float* g1_w     = (const float*)d_in[11];
  const float* g1_b     = (const float*)d_in[12];
  const float* g2_w     = (const float*)d_in[13];
  const float* g2_b     = (const float*)d_in[14];
  const float* wq       = (const float*)d_in[15];
  const float* wk       = (const float*)d_in[16];
  const float* wv       = (const float*)d_in[17];

  int* knn = (int*)d_ws;                                          // 512 KB
  unsigned short* wT = (unsigned short*)((char*)d_ws + 524288);   // 832 KB bf16
  float* out_res  = (float*)d_out;
  float* out_attn = (float*)d_out + (size_t)BB*MM*DP;

  prep_weights<<<1664, 256, 0, stream>>>(wq, fc1_w, wk, wv, d2_w, g1_w, g2_w, fc2_w, wT);
  knn_kernel<<<BB*MM/KNQ, 128, 0, stream>>>(xyz, query, knn);
  fused_mfma<<<BB*MM/4, 256, 0, stream>>>(
      xyz, features, query, fc1_b, fc2_b, d1_w, d1_b, d2_b, g1_b, g2_b,
      wT, knn, out_res, out_attn);
}